// Round 12
// baseline (64.323 us; speedup 1.0000x reference)
//
#include <hip/hip_runtime.h>

#define FDIM   251
#define NFILT  80
#define KPAD   256        // K padded to 8 chunks of 32 (zeros past 250)
#define T_IN   64000
#define T_OUT  63750      // 64000 - 251 + 1
#define NCHUNK 512        // output positions per block; wave owns contiguous 128
#define NFT    5          // filter tiles (16 filters each)
#define CPYLEN 392        // dwords per shifted copy; 392 % 32 == 8 -> bank stagger
#define XSTOT  (8 * CPYLEN)   // 12.5 KB LDS

typedef short bf16x8 __attribute__((ext_vector_type(8)));
typedef float f32x4  __attribute__((ext_vector_type(4)));

__device__ __forceinline__ unsigned short f2bf(float f) {
  unsigned int u = __float_as_uint(f);
  unsigned int r = (u + 0x7fffu + ((u >> 16) & 1u)) >> 16;   // RNE
  return (unsigned short)r;
}
__device__ __forceinline__ unsigned int packbf(float a, float b) {
  return (unsigned int)f2bf(a) | ((unsigned int)f2bf(b) << 16);
}

// ---------------------------------------------------------------------------
// Filter construction (validated rounds 1-11). Emits bf16 W[80][256].
// ---------------------------------------------------------------------------
__device__ __forceinline__ void norm_pm1_shared(float* a, float* scratch, int tid) {
  float v  = (tid < FDIM) ? a[tid] : 0.f;
  float mn = (tid < FDIM) ? v : 1e30f;
  float mx = (tid < FDIM) ? v : -1e30f;
  #pragma unroll
  for (int o = 32; o > 0; o >>= 1) {
    mn = fminf(mn, __shfl_down(mn, o));
    mx = fmaxf(mx, __shfl_down(mx, o));
  }
  const int wid = tid >> 6;
  if ((tid & 63) == 0) { scratch[wid] = mn; scratch[4 + wid] = mx; }
  __syncthreads();
  if (tid == 0) {
    scratch[0] = fminf(fminf(scratch[0], scratch[1]), fminf(scratch[2], scratch[3]));
    scratch[4] = fmaxf(fmaxf(scratch[4], scratch[5]), fmaxf(scratch[6], scratch[7]));
  }
  __syncthreads();
  const float gmn = scratch[0], gmx = scratch[4];
  const float nv = 2.f * (v - gmn) / (gmx - gmn + 1e-6f) - 1.f;
  __syncthreads();
  float s = (tid < FDIM) ? nv : 0.f;
  #pragma unroll
  for (int o = 32; o > 0; o >>= 1) s += __shfl_down(s, o);
  if ((tid & 63) == 0) scratch[wid] = s;
  __syncthreads();
  if (tid == 0) scratch[0] = (scratch[0] + scratch[1] + scratch[2] + scratch[3]) / 251.f;
  __syncthreads();
  const float mean = scratch[0];
  if (tid < FDIM) a[tid] = nv - mean;
  __syncthreads();
}

__global__ __launch_bounds__(256) void build_filters_kernel(
    const float* __restrict__ nf1, const float* __restrict__ nf2,
    const float* __restrict__ nf3, const float* __restrict__ nf4,
    const float* __restrict__ amp1, const float* __restrict__ amp2,
    unsigned short* __restrict__ Wbf) {
  __shared__ float ir1[FDIM], ir2[FDIM], casc[FDIM];
  __shared__ float scratch[8];
  const int f = blockIdx.x, tid = threadIdx.x;
  const float FS  = 16000.f;
  const float MF  = 50.f / 16000.f;
  const float PIF = 3.14159265358979323846f;
  const float TPI = 6.28318530717958647692f;

  const float f1 = fminf(fmaxf(fabsf(nf1[f]) + MF, 0.f), 0.5f);
  const float f2 = fminf(fmaxf(f1 + fabsf(nf2[f] - f1) + MF, 0.f), 0.5f);
  const float f3 = fminf(fmaxf(fabsf(nf3[f]) + MF, 0.f), 0.5f);
  const float f4 = fminf(fmaxf(f3 + fabsf(nf4[f] - f3) + MF, 0.f), 0.5f);
  const float a1 = fabsf(amp1[f]);
  const float a2 = fabsf(amp2[f]);

  if (tid < FDIM) {
    const float t = (float)(tid + 1) / FS;
    {
      const float fcs = 0.5f * (f1 + f2) * FS, bws = (f2 - f1) * FS;
      const float pb = PIF * bws;
      ir1[tid] = a1 * expf(-2.f * pb * pb * (t * t)) * cosf(TPI * fcs * t);
    }
    {
      const float fcs = 0.5f * (f3 + f4) * FS, bws = (f4 - f3) * FS;
      const float pb = PIF * bws;
      ir2[tid] = a2 * expf(-2.f * pb * pb * (t * t)) * cosf(TPI * fcs * t);
    }
  }
  __syncthreads();
  norm_pm1_shared(ir1, scratch, tid);
  norm_pm1_shared(ir2, scratch, tid);

  if (tid < FDIM) {
    const int i = tid;
    const int plo = (i - 125 > 0) ? (i - 125) : 0;
    const int phi = (i + 125 < 250) ? (i + 125) : 250;
    float s = 0.f;
    for (int p = plo; p <= phi; ++p) s += ir1[p] * ir2[p + 125 - i];
    casc[i] = s;
  }
  __syncthreads();
  norm_pm1_shared(casc, scratch, tid);

  if (tid < KPAD) {
    float v = 0.f;
    if (tid < FDIM) {
      const float win = 0.54f - 0.46f * cosf(TPI * ((float)tid / 250.f));
      v = casc[tid] * win;
    }
    Wbf[(size_t)f * KPAD + tid] = f2bf(v);
  }
}

// ---------------------------------------------------------------------------
// Implicit-GEMM conv, round-12: drain-efficiency bundle on the r7 lineage.
//  - operands SWAPPED (r4-validated): A = x window, B = W
//      -> lane (m,h) holds D[t' = 4h+r][f = m]: 4 CONSECUTIVE t per lane
//      -> store = 2 float2 per tile (2x fewer store instrs than r7's dwords;
//         float4 impossible: odd f-rows are 8B-aligned, T_OUT*4 % 16 == 8)
//  - NCHUNK 512: halves per-block latency -> halves the drain-tail quantum
//    (5000 blocks = 3.9 generations at 5 blocks/CU)
//  - __launch_bounds__(256,5): 5 blocks/CU (VGPR cap 102, live ~75; r6
//    spill lesson respected). LDS 12.5 KB.
// Fragment addressing identical to r4-r11 (validated). Same products, same
// chunk order -> bit-identical output (r4 confirmed absmax 0.125).
// ---------------------------------------------------------------------------
__global__ __launch_bounds__(256, 5) void conv_mfma_kernel(
    const float* __restrict__ xin, const unsigned short* __restrict__ Wbf,
    float* __restrict__ outp) {
  __shared__ __align__(16) unsigned int xs[XSTOT];
  const int tid = threadIdx.x;
  const int n0  = blockIdx.x * NCHUNK;
  const int ft  = blockIdx.y;
  const int b   = blockIdx.z;
  const int l   = tid & 63, w = tid >> 6;
  const int m   = l & 15, h = l >> 4;

  // ---- stage x as 8 shifted bf16-pair copies: C_j[i] = (x[2i+j], x[2i+j+1]) ----
  const float* xg = xin + (size_t)b * T_IN;
  for (int i = tid; i < CPYLEN - 4; i += 256) {
    float e[10];
    #pragma unroll
    for (int q = 0; q < 10; ++q) {
      const int g = n0 + 2 * i + q;
      e[q] = (g < T_IN) ? xg[g] : 0.f;
    }
    #pragma unroll
    for (int j = 0; j < 8; ++j)
      xs[j * CPYLEN + i] = packbf(e[j], e[j + 1]);
  }

  // ---- W fragments (B-operand): col f = m, k = 8*h + j + 32*c ----
  const short* Wp = (const short*)Wbf;
  bf16x8 wfr[8];
  #pragma unroll
  for (int c = 0; c < 8; ++c)
    wfr[c] = *(const bf16x8*)(Wp + (ft * 16 + m) * KPAD + c * 32 + h * 8);

  __syncthreads();

  // lane-constant A(x) addressing (validated r4-r11):
  // tile base t_loc, chunk c -> copy m&7, 16B-unit index t_loc/8 + lane_q + 4c
  const unsigned int* psrc = xs + (m & 7) * CPYLEN;
  const int lane_q = h + (m >> 3);
  const int tw0 = w * 128;                     // wave's local t base (8 tiles)
  const size_t rowm = ((size_t)b * NFILT + ft * 16 + m) * T_OUT;

  for (int u = 0; u < 4; ++u) {                // pairs of 16-t tiles, 2 chains
    const int qA = ((tw0 + u * 32) >> 3) + lane_q;
    f32x4 accA = (f32x4){0.f, 0.f, 0.f, 0.f};
    f32x4 accB = (f32x4){0.f, 0.f, 0.f, 0.f};

    #pragma unroll
    for (int c = 0; c < 8; ++c) {
      const bf16x8 xa = *(const bf16x8*)(psrc + 4 * (qA + 4 * c));
      const bf16x8 xb = *(const bf16x8*)(psrc + 4 * (qA + 2 + 4 * c));
      accA = __builtin_amdgcn_mfma_f32_16x16x32_bf16(xa, wfr[c], accA, 0, 0, 0);
      accB = __builtin_amdgcn_mfma_f32_16x16x32_bf16(xb, wfr[c], accB, 0, 0, 0);
    }

    // D rows = t' = 4h + r (consecutive), col = f = m
    const int tgA = n0 + tw0 + u * 32 + 4 * h;
    const int tgB = tgA + 16;
    if (tgA + 4 <= T_OUT) {
      *(float2*)&outp[rowm + tgA]     = make_float2(accA[0], accA[1]);
      *(float2*)&outp[rowm + tgA + 2] = make_float2(accA[2], accA[3]);
    } else {
      #pragma unroll
      for (int r = 0; r < 4; ++r)
        if (tgA + r < T_OUT) outp[rowm + tgA + r] = accA[r];
    }
    if (tgB + 4 <= T_OUT) {
      *(float2*)&outp[rowm + tgB]     = make_float2(accB[0], accB[1]);
      *(float2*)&outp[rowm + tgB + 2] = make_float2(accB[2], accB[3]);
    } else {
      #pragma unroll
      for (int r = 0; r < 4; ++r)
        if (tgB + r < T_OUT) outp[rowm + tgB + r] = accB[r];
    }
  }
}

// ---------------------------------------------------------------------------
extern "C" void kernel_launch(void* const* d_in, const int* in_sizes, int n_in,
                              void* d_out, int out_size, void* d_ws, size_t ws_size,
                              hipStream_t stream) {
  const float* x    = (const float*)d_in[0];
  const float* nf1  = (const float*)d_in[1];
  const float* nf2  = (const float*)d_in[2];
  const float* nf3  = (const float*)d_in[3];
  const float* nf4  = (const float*)d_in[4];
  const float* amp1 = (const float*)d_in[5];
  const float* amp2 = (const float*)d_in[6];
  unsigned short* Wbf = (unsigned short*)d_ws;   // 80*256*2 = 40 KB scratch
  float* out = (float*)d_out;

  build_filters_kernel<<<NFILT, 256, 0, stream>>>(nf1, nf2, nf3, nf4, amp1, amp2, Wbf);

  dim3 grid((T_OUT + NCHUNK - 1) / NCHUNK, NFT, 8);   // 125 x 5 x 8
  conv_mfma_kernel<<<grid, 256, 0, stream>>>(x, Wbf, out);
}